// Round 10
// baseline (515.862 us; speedup 1.0000x reference)
//
#include <hip/hip_runtime.h>
#include <math.h>

namespace {

constexpr int F   = 64;            // FEAT
constexpr int NA  = 128;           // atoms
constexpr int NB  = 8;             // batch
constexpr int EPN = NA*(NA-1);     // 16256 edges per sample
constexpr int K   = 16;            // radial basis
constexpr int L   = 9;             // irreps
constexpr int BE  = NB*EPN;        // 130048 total edges
constexpr int NNLF= NB*NA*L*F;     // 589824
constexpr int BNF = NB*NA*F;       // 65536
constexpr int GSP = 4;             // blocks per atom (grid partition)
constexpr int WPB = 2;             // waves per edge-block (128 threads)
constexpr int NSUB= 16;            // neighbors per wave (4*2*16 >= 127)
constexpr float SQ3 = 1.7320508075688772f;

__device__ __constant__ float BINOM[16] = {1.f,15.f,105.f,455.f,1365.f,3003.f,5005.f,6435.f,
                                           6435.f,5005.f,3003.f,1365.f,455.f,105.f,15.f,1.f};
__device__ __constant__ int DEGC[9] = {0,1,1,1,2,2,2,2,2};

__device__ inline float wred(float v){
  #pragma unroll
  for (int o=32;o>0;o>>=1) v += __shfl_xor(v, o, 64);
  return v;
}

// packed 4-value wave64 reduction: returns on every lane the total of v_{lane&3}
__device__ inline float qreduce(float v0, float v1, float v2, float v3, int lane){
  float a = ((lane&1)? v1 : v0) + __shfl_xor(((lane&1)? v0 : v1), 1, 64);
  float b = ((lane&1)? v3 : v2) + __shfl_xor(((lane&1)? v2 : v3), 1, 64);
  float r = ((lane&2)? b : a) + __shfl_xor(((lane&2)? a : b), 2, 64);
  r += __shfl_xor(r, 4, 64);
  r += __shfl_xor(r, 8, 64);
  r += __shfl_xor(r,16, 64);
  r += __shfl_xor(r,32, 64);
  return r;
}

// ---------------- prep: transposes, dsp = W2s@wout, zero d_out ----------------
__global__ void k_prep(const float* W1, const float* W2, const float* W1s,
                       const float* W2s, const float* wout,
                       float* W1T, float* W2T, float* W1sT, float* dsp,
                       float* outbuf){
  int idx = blockIdx.x*256 + threadIdx.x;
  if (idx < 6*F*F){
    int rem = idx % (F*F); int m = idx/(F*F); int g = rem/F, f = rem%F;
    W1T[idx] = W1[(m*F+f)*F+g];
    W2T[idx] = W2[(m*F+f)*F+g];
  } else if (idx < 6*F*F + F*F){
    int rem = idx - 6*F*F; int g = rem/F, f = rem%F;
    W1sT[rem] = W1s[f*F+g];
  } else if (idx < 6*F*F + F*F + F){
    int f = idx - 6*F*F - F*F;
    float s=0.f;
    for (int g=0; g<F; g++) s += W2s[f*F+g]*wout[g];
    dsp[f]=s;
  } else if (idx < 6*F*F + F*F + F + NB + NB*NA*3){
    outbuf[idx - (6*F*F + F*F + F)] = 0.f;   // Eout + Fout zero (atomic targets)
  }
}

// ---------------- per-edge geometry: u, 1/r, R=rad*cut, R'=d(rad*cut)/dr ------
__global__ void k_geom(const float* __restrict__ pos, const int* __restrict__ dsti,
                       const int* __restrict__ srci,
                       float* __restrict__ U, float* __restrict__ Rr,
                       float* __restrict__ Rp){
  int idx = blockIdx.x*256 + threadIdx.x;
  if (idx >= BE) return;
  int b = idx / EPN, e = idx % EPN;
  int d = dsti[e], s = srci[e];
  const float* pb = pos + (size_t)b*NA*3;
  float dx = pb[s*3+0]-pb[d*3+0];
  float dy = pb[s*3+1]-pb[d*3+1];
  float dz = pb[s*3+2]-pb[d*3+2];
  float ss = dx*dx+dy*dy+dz*dz + 1e-12f;
  float r  = sqrtf(ss);
  float ir = 1.f/r;
  U[(size_t)idx*4+0]=dx*ir; U[(size_t)idx*4+1]=dy*ir;
  U[(size_t)idx*4+2]=dz*ir; U[(size_t)idx*4+3]=ir;
  float w = 1.f/(1.f+r), v = 1.f - w;
  float wp[16], vp[16];
  wp[0]=1.f; vp[0]=1.f;
  #pragma unroll
  for (int k=1;k<16;k++){ wp[k]=wp[k-1]*w; vp[k]=vp[k-1]*v; }
  float t = (r*0.2f)*(r*0.2f);
  float cut=0.f, dcut=0.f;
  if (t < 1.f){
    float e1 = 1.f - t;
    float m  = fmaxf(e1, 1e-12f);
    cut = expf(1.f - 1.f/m);
    if (e1 > 1e-12f) dcut = -cut/(e1*e1) * (2.f*r*0.04f);
  }
  float nww = -w*w;
  #pragma unroll
  for (int k=0;k<16;k++){
    float rad = BINOM[k]*wp[k]*vp[15-k];
    float t1 = (k>0)  ? (float)k      * wp[k-1]*vp[15-k] : 0.f;
    float t2 = (k<15) ? (float)(15-k) * wp[k]  *vp[14-k] : 0.f;
    float dradr = BINOM[k]*(t1-t2)*nww;
    Rr[(size_t)idx*16+k] = rad*cut;
    Rp[(size_t)idx*16+k] = dradr*cut + rad*dcut;
  }
}

// ---------------- x init ------------------------------------------------------
__global__ void k_init_x(const int* __restrict__ z, const float* __restrict__ embed,
                         float* __restrict__ x0){
  int b = blockIdx.x / NA, n = blockIdx.x % NA, f = threadIdx.x;
  int zi = z[b*NA+n];
  float* row = x0 + ((size_t)(b*NA+n))*L*F;
  row[f] = embed[(size_t)zi*F+f];
  #pragma unroll
  for (int l=1;l<L;l++) row[l*F+f]=0.f;
}

// ---------------- layer edge forward (2-wave blocks, GSP=4, LDS combine) ------
template<bool FIRST>
__global__ __launch_bounds__(128) void k_edge_fwd(const float* __restrict__ x,
    const float* __restrict__ WA, const float* __restrict__ WB,
    const float* __restrict__ U, const float* __restrict__ Rr,
    float* __restrict__ aggP){
  __shared__ float sh[WPB][L*F];
  int bid = blockIdx.x;
  int g = bid & (GSP-1), bn = bid >> 2;
  int b = bn >> 7, n = bn & (NA-1);
  int t = threadIdx.x, f = t&63, wv = t>>6;
  float wa[K], wb[K];
  #pragma unroll
  for (int k=0;k<K;k++){ wa[k]=WA[k*F+f]; wb[k]=WB[k*F+f]; }
  float acc[L];
  #pragma unroll
  for (int l=0;l<L;l++) acc[l]=0.f;
  const float* xb = x + (size_t)b*NA*L*F;
  int c0 = g*(WPB*NSUB) + wv*NSUB, c1 = min(c0+NSUB, NA-1);
  #pragma unroll 2
  for (int c=c0; c<c1; ++c){
    int e = n*(NA-1)+c;
    int j = c + (c>=n);
    size_t ge = (size_t)b*EPN + e;
    const float* Re = Rr + ge*K;
    float RA=0.f, RB=0.f;
    #pragma unroll
    for (int k=0;k<K;k++){ float rk=Re[k]; RA += rk*wa[k]; RB += rk*wb[k]; }
    float ux=U[ge*4+0], uy=U[ge*4+1], uz=U[ge*4+2];
    float Y4=SQ3*ux*uy, Y5=SQ3*uy*uz, Y6=0.5f*(3.f*uz*uz-1.f);
    float Y7=SQ3*ux*uz, Y8=0.5f*SQ3*(ux*ux-uy*uy);
    const float* xr = xb + (size_t)j*L*F + f;
    float xs0 = xr[0];
    float t1 = RA*xs0;
    acc[0] += t1 + xs0*RB;
    if (FIRST){
      acc[1] += ux*t1; acc[2] += uy*t1; acc[3] += uz*t1;
      acc[4] += Y4*t1; acc[5] += Y5*t1; acc[6] += Y6*t1;
      acc[7] += Y7*t1; acc[8] += Y8*t1;
    } else {
      acc[1] += ux*t1 + xr[1*F]*RB;
      acc[2] += uy*t1 + xr[2*F]*RB;
      acc[3] += uz*t1 + xr[3*F]*RB;
      acc[4] += Y4*t1 + xr[4*F]*RB;
      acc[5] += Y5*t1 + xr[5*F]*RB;
      acc[6] += Y6*t1 + xr[6*F]*RB;
      acc[7] += Y7*t1 + xr[7*F]*RB;
      acc[8] += Y8*t1 + xr[8*F]*RB;
    }
  }
  #pragma unroll
  for (int l=0;l<L;l++) sh[wv][l*F+f] = acc[l];
  __syncthreads();
  float* ar = aggP + (size_t)g*NNLF + (size_t)bn*L*F;
  for (int idx=t; idx<L*F; idx+=128)
    ar[idx] = sh[0][idx]+sh[1][idx];
}

// ---------------- layer node forward (4 waves, l-split, 4 slabs) --------------
__global__ __launch_bounds__(256) void k_node_fwd(const float* __restrict__ x,
    const float* __restrict__ aggP, const float* __restrict__ W1,
    const float* __restrict__ b1, const float* __restrict__ W2,
    float* __restrict__ y2out, float* __restrict__ xout){
  __shared__ float sh[L*F];
  __shared__ float yb[L*F];
  __shared__ float zb[L*F];
  int t = threadIdx.x, g = t&63, w = t>>6;
  size_t base = ((size_t)blockIdx.x)*L*F;
  for (int idx=t; idx<L*F; idx+=256){
    float s = x[base+idx];
    #pragma unroll
    for (int sl=0; sl<GSP; sl++) s += aggP[(size_t)sl*NNLF + base + idx];
    sh[idx]=s;
  }
  __syncthreads();
  for (int l=w; l<L; l+=4){
    const float* W = W1 + DEGC[l]*F*F + g;
    float s=0.f;
    for (int ff=0; ff<F; ff++) s += sh[l*F+ff]*W[(size_t)ff*F];
    if (l==0) s += b1[g];
    y2out[base+l*F+g]=s;
    yb[l*F+g]=s;
  }
  __syncthreads();
  float sv = yb[g];
  float sg = 1.f/(1.f+expf(-sv));
  for (int l=w; l<L; l+=4)
    zb[l*F+g] = (l==0)? sv*sg : yb[l*F+g]*sg;
  __syncthreads();
  for (int l=w; l<L; l+=4){
    const float* W = W2 + DEGC[l]*F*F + g;
    float s=0.f;
    for (int ff=0; ff<F; ff++) s += zb[l*F+ff]*W[(size_t)ff*F];
    xout[base+l*F+g] = x[base+l*F+g] + s;
  }
}

// ---------------- readout edge forward (2-wave, GSP=4, LDS combine) -----------
__global__ __launch_bounds__(128) void k_redge_fwd(const float* __restrict__ x2,
    const float* __restrict__ WA2, const float* __restrict__ WB2,
    const float* __restrict__ U, const float* __restrict__ Rr,
    float* __restrict__ yRp){
  __shared__ float sh[WPB][F];
  int bid = blockIdx.x;
  int g = bid & (GSP-1), bn = bid >> 2;
  int b = bn >> 7, n = bn & (NA-1);
  int t = threadIdx.x, f = t&63, wv = t>>6;
  float wa[K], wb[K];
  #pragma unroll
  for (int k=0;k<K;k++){ wa[k]=WA2[k*F+f]; wb[k]=WB2[k*F+f]; }
  float acc=0.f;
  const float* xb = x2 + (size_t)b*NA*L*F;
  int c0 = g*(WPB*NSUB) + wv*NSUB, c1 = min(c0+NSUB, NA-1);
  #pragma unroll 2
  for (int c=c0; c<c1; ++c){
    int e = n*(NA-1)+c;
    int j = c + (c>=n);
    size_t ge = (size_t)b*EPN + e;
    const float* Re = Rr + ge*K;
    float RA=0.f, RB=0.f;
    #pragma unroll
    for (int k=0;k<K;k++){ float rk=Re[k]; RA += rk*wa[k]; RB += rk*wb[k]; }
    float ux=U[ge*4+0], uy=U[ge*4+1], uz=U[ge*4+2];
    const float* xr = xb + (size_t)j*L*F + f;
    float xs0 = xr[0];
    float T = xs0
            + ux*xr[1*F] + uy*xr[2*F] + uz*xr[3*F]
            + (SQ3*ux*uy)*xr[4*F] + (SQ3*uy*uz)*xr[5*F]
            + (0.5f*(3.f*uz*uz-1.f))*xr[6*F]
            + (SQ3*ux*uz)*xr[7*F] + (0.5f*SQ3*(ux*ux-uy*uy))*xr[8*F];
    acc += RA*xs0 + RB*T;
  }
  sh[wv][f]=acc;
  __syncthreads();
  if (t < F)
    yRp[(size_t)g*BNF + (size_t)bn*F + t] = sh[0][t]+sh[1][t];
}

// ---------------- readout node forward (4 waves, ff-split, 4 slabs) -----------
__global__ __launch_bounds__(256) void k_rnode_fwd(const int* __restrict__ z,
    const float* __restrict__ x2, const float* __restrict__ yRp,
    const float* __restrict__ W1s, const float* __restrict__ b1s,
    const float* __restrict__ W2s, const float* __restrict__ wout,
    const float* __restrict__ ebias, float* __restrict__ pW, float* Eout){
  __shared__ float sh[F];
  __shared__ float part[4][F];
  int t = threadIdx.x, g = t&63, w = t>>6;
  int bnn = blockIdx.x;
  int b = bnn >> 7;
  size_t base = (size_t)bnn*L*F;
  size_t nb   = (size_t)bnn*F;
  if (t < F){
    float s = x2[base+t];
    #pragma unroll
    for (int sl=0; sl<GSP; sl++) s += yRp[(size_t)sl*BNF + nb + t];
    sh[t]=s;
  }
  __syncthreads();
  float pp=0.f;
  for (int ff=w*16; ff<w*16+16; ff++) pp += sh[ff]*W1s[(size_t)ff*F+g];
  part[w][g]=pp;
  __syncthreads();
  float p = part[0][g]+part[1][g]+part[2][g]+part[3][g] + b1s[g];
  if (w==0) pW[nb+g]=p;
  float sp = p/(1.f+expf(-p));
  __syncthreads();
  if (w==0) sh[g]=sp;
  __syncthreads();
  float h=0.f;
  for (int ff=w*16; ff<w*16+16; ff++) h += sh[ff]*W2s[(size_t)ff*F+g];
  part[w][g]=h;
  __syncthreads();
  if (w==0){
    float h2 = part[0][g]+part[1][g]+part[2][g]+part[3][g];
    float x0v = x2[base+g];
    float en = wred((x0v+h2)*wout[g]);
    if (g==0) atomicAdd(Eout+b, en + ebias[z[bnn]]);
  }
}

// ---------------- readout node backward (4 waves, ff-split) -------------------
__global__ __launch_bounds__(256) void k_rnode_bwd(const float* __restrict__ pW,
    const float* __restrict__ dsp, const float* __restrict__ W1sT,
    const float* __restrict__ wout, float* __restrict__ dyR, float* __restrict__ dxA){
  __shared__ float sh[F];
  __shared__ float part[4][F];
  int t = threadIdx.x, g = t&63, w = t>>6;
  size_t nb = (size_t)blockIdx.x*F;
  size_t base = (size_t)blockIdx.x*L*F;
  if (t < F){
    float p  = pW[nb+t];
    float sgm = 1.f/(1.f+expf(-p));
    sh[t] = dsp[t]*sgm*(1.f + p*(1.f-sgm));
  }
  __syncthreads();
  float s=0.f;
  for (int ff=w*16; ff<w*16+16; ff++) s += sh[ff]*W1sT[(size_t)ff*F+g];
  part[w][g]=s;
  __syncthreads();
  if (w==0){
    float dh1 = part[0][g]+part[1][g]+part[2][g]+part[3][g];
    dyR[nb+g]=dh1;
    dxA[base+g] = wout[g]+dh1;
  }
  for (int idx=t; idx<(L-1)*F; idx+=256) dxA[base+F+idx]=0.f;
}

// ---------------- readout edge backward (2-wave, GSP=4, LDS combine) ----------
__global__ __launch_bounds__(128) void k_redge_bwd(const float* __restrict__ x2,
    const float* __restrict__ WA2, const float* __restrict__ WB2,
    const float* __restrict__ U, const float* __restrict__ Rr,
    const float* __restrict__ Rp, const float* __restrict__ dyR,
    float* __restrict__ partP, float* Fout){
  __shared__ float sh[WPB][L*F];
  __shared__ float shS[WPB][4];
  int bid = blockIdx.x;
  int g = bid & (GSP-1), bn = bid >> 2;
  int b = bn >> 7, j = bn & (NA-1);
  int t = threadIdx.x, f = t&63, wv = t>>6, m = f&3;
  float wa[K], wb[K];
  #pragma unroll
  for (int k=0;k<K;k++){ wa[k]=WA2[k*F+f]; wb[k]=WB2[k*F+f]; }
  size_t xbase = ((size_t)bn)*L*F;
  float xs[L];
  #pragma unroll
  for (int l=0;l<L;l++) xs[l]=x2[xbase+l*F+f];
  float acc[L];
  #pragma unroll
  for (int l=0;l<L;l++) acc[l]=0.f;
  float sdd=0.f;
  int i0 = g*(WPB*NSUB) + wv*NSUB, i1 = min(i0+NSUB, NA-1);
  for (int ii=i0; ii<i1; ++ii){
    int i = ii + (ii>=j);
    int c = (j<i)? j : j-1;
    size_t ge = (size_t)b*EPN + i*(NA-1)+c;
    float gv = dyR[(size_t)(b*NA+i)*F+f];
    const float* Re = Rr + ge*K;
    const float* Pe = Rp + ge*K;
    float RA=0.f,RB=0.f,PA=0.f,PB=0.f;
    #pragma unroll
    for (int k=0;k<K;k++){ float rk=Re[k],pk=Pe[k];
      RA+=rk*wa[k]; RB+=rk*wb[k]; PA+=pk*wa[k]; PB+=pk*wb[k]; }
    float ux=U[ge*4+0], uy=U[ge*4+1], uz=U[ge*4+2], ir=U[ge*4+3];
    float Y4=SQ3*ux*uy, Y5=SQ3*uy*uz, Y6=0.5f*(3.f*uz*uz-1.f);
    float Y7=SQ3*ux*uz, Y8=0.5f*SQ3*(ux*ux-uy*uy);
    float T = xs[0] + ux*xs[1]+uy*xs[2]+uz*xs[3]
            + Y4*xs[4]+Y5*xs[5]+Y6*xs[6]+Y7*xs[7]+Y8*xs[8];
    float X0 = xs[1] + SQ3*(uy*xs[4]+uz*xs[7]+ux*xs[8]);
    float X1 = xs[2] + SQ3*(ux*xs[4]+uz*xs[5]-uy*xs[8]);
    float X2 = xs[3] + SQ3*(uy*xs[5]+ux*xs[7]) + 3.f*uz*xs[6];
    acc[0] += gv*(RA+RB);
    acc[1] += gv*ux*RB; acc[2] += gv*uy*RB; acc[3] += gv*uz*RB;
    acc[4] += gv*Y4*RB; acc[5] += gv*Y5*RB; acc[6] += gv*Y6*RB;
    acc[7] += gv*Y7*RB; acc[8] += gv*Y8*RB;
    float gRB = gv*RB;
    float dotX = ux*X0 + uy*X1 + uz*X2;
    float v3 = gv*(xs[0]*PA + T*PB) - gRB*dotX*ir;
    float r4 = qreduce(gRB*X0, gRB*X1, gRB*X2, v3, f);
    float SR = __shfl(r4, f|3, 64);
    float um = (m==0)?ux : (m==1)?uy : (m==2)?uz : 0.f;
    float dd = r4*ir + SR*um;
    if (f<3) atomicAdd(&Fout[(size_t)(b*NA+i)*3+f], dd);
    sdd += dd;
  }
  #pragma unroll
  for (int l=0;l<L;l++) sh[wv][l*F+f]=acc[l];
  if (f<3) shS[wv][f]=sdd;
  __syncthreads();
  float* ar = partP + (size_t)g*NNLF + xbase;
  for (int idx=t; idx<L*F; idx+=128)
    ar[idx] = sh[0][idx]+sh[1][idx];
  if (t<3)
    atomicAdd(&Fout[(size_t)bn*3+t], -(shS[0][t]+shS[1][t]));
}

// ---------------- layer node backward (4 waves, l-split, 4 slabs) -------------
template<bool WDX>
__global__ __launch_bounds__(256) void k_node_bwd(const float* __restrict__ dxIn,
    const float* __restrict__ partP, const float* __restrict__ y2W,
    const float* __restrict__ W1T, const float* __restrict__ W2T,
    float* __restrict__ dagg, float* __restrict__ dxOut){
  __shared__ float A[L*F];
  __shared__ float D3[L*F];
  __shared__ float Bb[L*F];
  __shared__ float prt[4][F];
  int t = threadIdx.x, g = t&63, w = t>>6;
  size_t base = ((size_t)blockIdx.x)*L*F;
  for (int idx=t; idx<L*F; idx+=256){
    float s = dxIn[base+idx];
    #pragma unroll
    for (int sl=0; sl<GSP; sl++) s += partP[(size_t)sl*NNLF + base + idx];
    A[idx]=s;
  }
  __syncthreads();
  float pc=0.f;
  for (int l=w; l<L; l+=4){
    const float* W = W2T + DEGC[l]*F*F + g;
    float s=0.f;
    for (int ff=0; ff<F; ff++) s += A[l*F+ff]*W[(size_t)ff*F];
    D3[l*F+g]=s;
    if (l>0) pc += s * y2W[base+l*F+g];
  }
  prt[w][g]=pc;
  __syncthreads();
  float sv = y2W[base+g];
  float sg = 1.f/(1.f+expf(-sv));
  for (int l=w; l<L; l+=4){
    float v;
    if (l==0){
      float sum = prt[0][g]+prt[1][g]+prt[2][g]+prt[3][g];
      v = D3[g]*sg*(1.f+sv*(1.f-sg)) + sum*sg*(1.f-sg);
    } else {
      v = D3[l*F+g]*sg;
    }
    Bb[l*F+g]=v;
  }
  __syncthreads();
  for (int l=w; l<L; l+=4){
    const float* W = W1T + DEGC[l]*F*F + g;
    float s=0.f;
    for (int ff=0; ff<F; ff++) s += Bb[l*F+ff]*W[(size_t)ff*F];
    dagg[base+l*F+g]=s;
    if (WDX) dxOut[base+l*F+g] = A[l*F+g] + s;
  }
}

// ---------------- layer edge backward (2-wave, GSP=4, LDS combine) ------------
template<bool WDX, bool FIRST>
__global__ __launch_bounds__(128) void k_edge_bwd(const float* __restrict__ xI,
    const float* __restrict__ WA, const float* __restrict__ WB,
    const float* __restrict__ U, const float* __restrict__ Rr,
    const float* __restrict__ Rp, const float* __restrict__ dagg,
    float* __restrict__ partP, float* Fout){
  __shared__ float sh[WPB][L*F];
  __shared__ float shS[WPB][4];
  int bid = blockIdx.x;
  int g = bid & (GSP-1), bn = bid >> 2;
  int b = bn >> 7, j = bn & (NA-1);
  int t = threadIdx.x, f = t&63, wv = t>>6, m = f&3;
  float wa[K], wb[K];
  #pragma unroll
  for (int k=0;k<K;k++){ wa[k]=WA[k*F+f]; wb[k]=WB[k*F+f]; }
  size_t xbase = ((size_t)bn)*L*F;
  float xs[L];
  xs[0] = xI[xbase+f];
  #pragma unroll
  for (int l=1;l<L;l++) xs[l] = FIRST ? 0.f : xI[xbase+l*F+f];
  float acc[L]; float acc0=0.f;
  #pragma unroll
  for (int l=0;l<L;l++) acc[l]=0.f;
  float sdd=0.f;
  int i0 = g*(WPB*NSUB) + wv*NSUB, i1 = min(i0+NSUB, NA-1);
  for (int ii=i0; ii<i1; ++ii){
    int i = ii + (ii>=j);
    int c = (j<i)? j : j-1;
    size_t ge = (size_t)b*EPN + i*(NA-1)+c;
    const float* gr = dagg + ((size_t)(b*NA+i))*L*F + f;
    float gl[L];
    #pragma unroll
    for (int l=0;l<L;l++) gl[l]=gr[l*F];
    const float* Re = Rr + ge*K;
    const float* Pe = Rp + ge*K;
    float RA=0.f,RB=0.f,PA=0.f,PB=0.f;
    #pragma unroll
    for (int k=0;k<K;k++){ float rk=Re[k],pk=Pe[k];
      RA+=rk*wa[k]; RB+=rk*wb[k]; PA+=pk*wa[k]; PB+=pk*wb[k]; }
    float ux=U[ge*4+0], uy=U[ge*4+1], uz=U[ge*4+2], ir=U[ge*4+3];
    float Y4=SQ3*ux*uy, Y5=SQ3*uy*uz, Y6=0.5f*(3.f*uz*uz-1.f);
    float Y7=SQ3*ux*uz, Y8=0.5f*SQ3*(ux*ux-uy*uy);
    float gy = gl[0] + gl[1]*ux+gl[2]*uy+gl[3]*uz
             + gl[4]*Y4+gl[5]*Y5+gl[6]*Y6+gl[7]*Y7+gl[8]*Y8;
    float gx;
    if (FIRST){
      gx = gl[0]*xs[0];
    } else {
      gx = 0.f;
      #pragma unroll
      for (int l=0;l<L;l++) gx += gl[l]*xs[l];
    }
    float G0 = gl[1] + SQ3*(uy*gl[4]+uz*gl[7]+ux*gl[8]);
    float G1 = gl[2] + SQ3*(ux*gl[4]+uz*gl[5]-uy*gl[8]);
    float G2 = gl[3] + SQ3*(uy*gl[5]+ux*gl[7]) + 3.f*uz*gl[6];
    if (WDX){
      acc0 += gy*RA;
      #pragma unroll
      for (int l=0;l<L;l++) acc[l] += gl[l]*RB;
    }
    float cm = RA*xs[0];
    float dotG = ux*G0 + uy*G1 + uz*G2;
    float v3 = gy*xs[0]*PA + gx*PB - cm*dotG*ir;
    float r4 = qreduce(cm*G0, cm*G1, cm*G2, v3, f);
    float SR = __shfl(r4, f|3, 64);
    float um = (m==0)?ux : (m==1)?uy : (m==2)?uz : 0.f;
    float dd = r4*ir + SR*um;
    if (f<3) atomicAdd(&Fout[(size_t)(b*NA+i)*3+f], dd);
    sdd += dd;
  }
  if (WDX){
    sh[wv][f] = acc0 + acc[0];
    #pragma unroll
    for (int l=1;l<L;l++) sh[wv][l*F+f] = acc[l];
  }
  if (f<3) shS[wv][f]=sdd;
  __syncthreads();
  if (WDX){
    float* ar = partP + (size_t)g*NNLF + xbase;
    for (int idx=t; idx<L*F; idx+=128)
      ar[idx] = sh[0][idx]+sh[1][idx];
  }
  if (t<3)
    atomicAdd(&Fout[(size_t)bn*3+t], -(shS[0][t]+shS[1][t]));
}

} // anonymous namespace

extern "C" void kernel_launch(void* const* d_in, const int* in_sizes, int n_in,
                              void* d_out, int out_size, void* d_ws, size_t ws_size,
                              hipStream_t stream){
  (void)in_sizes; (void)n_in; (void)out_size; (void)ws_size;
  const int*   z     = (const int*)  d_in[0];
  const float* pos   = (const float*)d_in[1];
  const float* emb   = (const float*)d_in[2];
  const float* WA    = (const float*)d_in[3];
  const float* WB    = (const float*)d_in[4];
  const float* W1    = (const float*)d_in[5];
  const float* b1    = (const float*)d_in[6];
  const float* W2    = (const float*)d_in[7];
  const float* W1s   = (const float*)d_in[8];
  const float* b1s   = (const float*)d_in[9];
  const float* W2s   = (const float*)d_in[10];
  const float* wout  = (const float*)d_in[11];
  const float* ebias = (const float*)d_in[12];
  const int*   dsti  = (const int*)  d_in[13];
  const int*   srci  = (const int*)  d_in[14];

  float* w    = (float*)d_ws;
  float* U    = w;                          // BE*4
  float* Rr   = U    + (size_t)BE*4;        // BE*16
  float* Rp   = Rr   + (size_t)BE*16;       // BE*16
  float* x0   = Rp   + (size_t)BE*16;       // NNLF
  float* x1   = x0   + NNLF;                // NNLF
  float* x2   = x1   + NNLF;                // NNLF
  float* y2b  = x2   + NNLF;                // 2*NNLF
  float* part = y2b  + 2*(size_t)NNLF;      // GSP*NNLF
  float* yRp  = part + (size_t)GSP*NNLF;    // GSP*BNF
  float* pW   = yRp  + (size_t)GSP*BNF;     // BNF
  float* dyR  = pW   + BNF;                 // BNF
  float* dxA  = dyR  + BNF;                 // NNLF
  float* dxO  = dxA  + NNLF;                // NNLF
  float* dagg = dxO  + NNLF;                // NNLF
  float* W1T  = dagg + NNLF;                // 6*F*F
  float* W2T  = W1T  + 6*F*F;               // 6*F*F
  float* W1sT = W2T  + 6*F*F;               // F*F
  float* dspv = W1sT + F*F;                 // F

  float* Eout = (float*)d_out;
  float* Fout = Eout + NB;

  dim3 bn(NB*NA);
  dim3 be(NB*NA*GSP);

  k_prep  <<<126, 256, 0, stream>>>(W1, W2, W1s, W2s, wout, W1T, W2T, W1sT, dspv, Eout);
  k_geom  <<<(BE+255)/256, 256, 0, stream>>>(pos, dsti, srci, U, Rr, Rp);
  k_init_x<<<bn, 64, 0, stream>>>(z, emb, x0);

  // layer 0
  k_edge_fwd<true ><<<be, 128, 0, stream>>>(x0, WA,     WB,     U, Rr, part);
  k_node_fwd<<<bn, 256, 0, stream>>>(x0, part, W1,       b1,   W2,       y2b,      x1);
  // layer 1
  k_edge_fwd<false><<<be, 128, 0, stream>>>(x1, WA+K*F, WB+K*F, U, Rr, part);
  k_node_fwd<<<bn, 256, 0, stream>>>(x1, part, W1+3*F*F, b1+F, W2+3*F*F, y2b+NNLF, x2);
  // readout
  k_redge_fwd<<<be, 128, 0, stream>>>(x2, WA+2*K*F, WB+2*K*F, U, Rr, yRp);
  k_rnode_fwd<<<bn, 256, 0, stream>>>(z, x2, yRp, W1s, b1s, W2s, wout, ebias, pW, Eout);

  // backward
  k_rnode_bwd<<<bn, 256, 0, stream>>>(pW, dspv, W1sT, wout, dyR, dxA);
  k_redge_bwd<<<be, 128, 0, stream>>>(x2, WA+2*K*F, WB+2*K*F, U, Rr, Rp, dyR, part, Fout);
  // layer 1 bwd
  k_node_bwd<true ><<<bn, 256, 0, stream>>>(dxA, part, y2b+NNLF, W1T+3*F*F, W2T+3*F*F, dagg, dxO);
  k_edge_bwd<true ,false><<<be, 128, 0, stream>>>(x1, WA+K*F, WB+K*F, U, Rr, Rp, dagg, part, Fout);
  // layer 0 bwd
  k_node_bwd<false><<<bn, 256, 0, stream>>>(dxO, part, y2b, W1T, W2T, dagg, nullptr);
  k_edge_bwd<false,true ><<<be, 128, 0, stream>>>(x0, WA, WB, U, Rr, Rp, dagg, nullptr, Fout);
}

// Round 11
// 414.246 us; speedup vs baseline: 1.2453x; 1.2453x over previous
//
#include <hip/hip_runtime.h>
#include <math.h>

namespace {

constexpr int F   = 64;            // FEAT
constexpr int NA  = 128;           // atoms
constexpr int NB  = 8;             // batch
constexpr int EPN = NA*(NA-1);     // 16256 edges per sample
constexpr int K   = 16;            // radial basis
constexpr int L   = 9;             // irreps
constexpr int BE  = NB*EPN;        // 130048 total edges
constexpr int NNLF= NB*NA*L*F;     // 589824
constexpr int BNF = NB*NA*F;       // 65536
constexpr int GSP = 4;             // blocks per atom (grid partition)
constexpr int WPB = 2;             // waves per edge-block (128 threads)
constexpr int NSUB= 16;            // neighbors per wave (4*2*16 >= 127)
constexpr float SQ3 = 1.7320508075688772f;

__device__ __constant__ float BINOM[16] = {1.f,15.f,105.f,455.f,1365.f,3003.f,5005.f,6435.f,
                                           6435.f,5005.f,3003.f,1365.f,455.f,105.f,15.f,1.f};
__device__ __constant__ int DEGC[9] = {0,1,1,1,2,2,2,2,2};

__device__ inline float wred(float v){
  #pragma unroll
  for (int o=32;o>0;o>>=1) v += __shfl_xor(v, o, 64);
  return v;
}

// packed 4-value wave64 reduction: returns on every lane the total of v_{lane&3}
__device__ inline float qreduce(float v0, float v1, float v2, float v3, int lane){
  float a = ((lane&1)? v1 : v0) + __shfl_xor(((lane&1)? v0 : v1), 1, 64);
  float b = ((lane&1)? v3 : v2) + __shfl_xor(((lane&1)? v2 : v3), 1, 64);
  float r = ((lane&2)? b : a) + __shfl_xor(((lane&2)? a : b), 2, 64);
  r += __shfl_xor(r, 4, 64);
  r += __shfl_xor(r, 8, 64);
  r += __shfl_xor(r,16, 64);
  r += __shfl_xor(r,32, 64);
  return r;
}

// ---------------- prep: transposes, dsp = W2s@wout, zero d_out ----------------
__global__ void k_prep(const float* W1, const float* W2, const float* W1s,
                       const float* W2s, const float* wout,
                       float* W1T, float* W2T, float* W1sT, float* dsp,
                       float* outbuf){
  int idx = blockIdx.x*256 + threadIdx.x;
  if (idx < 6*F*F){
    int rem = idx % (F*F); int m = idx/(F*F); int g = rem/F, f = rem%F;
    W1T[idx] = W1[(m*F+f)*F+g];
    W2T[idx] = W2[(m*F+f)*F+g];
  } else if (idx < 6*F*F + F*F){
    int rem = idx - 6*F*F; int g = rem/F, f = rem%F;
    W1sT[rem] = W1s[f*F+g];
  } else if (idx < 6*F*F + F*F + F){
    int f = idx - 6*F*F - F*F;
    float s=0.f;
    for (int g=0; g<F; g++) s += W2s[f*F+g]*wout[g];
    dsp[f]=s;
  } else if (idx < 6*F*F + F*F + F + NB + NB*NA*3){
    outbuf[idx - (6*F*F + F*F + F)] = 0.f;   // Eout + Fout zero (atomic targets)
  }
}

// ---------------- per-edge geometry: u, 1/r, R=rad*cut, R'=d(rad*cut)/dr ------
__global__ void k_geom(const float* __restrict__ pos, const int* __restrict__ dsti,
                       const int* __restrict__ srci,
                       float* __restrict__ U, float* __restrict__ Rr,
                       float* __restrict__ Rp){
  int idx = blockIdx.x*256 + threadIdx.x;
  if (idx >= BE) return;
  int b = idx / EPN, e = idx % EPN;
  int d = dsti[e], s = srci[e];
  const float* pb = pos + (size_t)b*NA*3;
  float dx = pb[s*3+0]-pb[d*3+0];
  float dy = pb[s*3+1]-pb[d*3+1];
  float dz = pb[s*3+2]-pb[d*3+2];
  float ss = dx*dx+dy*dy+dz*dz + 1e-12f;
  float r  = sqrtf(ss);
  float ir = 1.f/r;
  U[(size_t)idx*4+0]=dx*ir; U[(size_t)idx*4+1]=dy*ir;
  U[(size_t)idx*4+2]=dz*ir; U[(size_t)idx*4+3]=ir;
  float w = 1.f/(1.f+r), v = 1.f - w;
  float wp[16], vp[16];
  wp[0]=1.f; vp[0]=1.f;
  #pragma unroll
  for (int k=1;k<16;k++){ wp[k]=wp[k-1]*w; vp[k]=vp[k-1]*v; }
  float t = (r*0.2f)*(r*0.2f);
  float cut=0.f, dcut=0.f;
  if (t < 1.f){
    float e1 = 1.f - t;
    float m  = fmaxf(e1, 1e-12f);
    cut = expf(1.f - 1.f/m);
    if (e1 > 1e-12f) dcut = -cut/(e1*e1) * (2.f*r*0.04f);
  }
  float nww = -w*w;
  #pragma unroll
  for (int k=0;k<16;k++){
    float rad = BINOM[k]*wp[k]*vp[15-k];
    float t1 = (k>0)  ? (float)k      * wp[k-1]*vp[15-k] : 0.f;
    float t2 = (k<15) ? (float)(15-k) * wp[k]  *vp[14-k] : 0.f;
    float dradr = BINOM[k]*(t1-t2)*nww;
    Rr[(size_t)idx*16+k] = rad*cut;
    Rp[(size_t)idx*16+k] = dradr*cut + rad*dcut;
  }
}

// ---------------- x init ------------------------------------------------------
__global__ void k_init_x(const int* __restrict__ z, const float* __restrict__ embed,
                         float* __restrict__ x0){
  int b = blockIdx.x / NA, n = blockIdx.x % NA, f = threadIdx.x;
  int zi = z[b*NA+n];
  float* row = x0 + ((size_t)(b*NA+n))*L*F;
  row[f] = embed[(size_t)zi*F+f];
  #pragma unroll
  for (int l=1;l<L;l++) row[l*F+f]=0.f;
}

// ---------------- layer edge forward (2-wave blocks, GSP=4, LDS combine) ------
template<bool FIRST>
__global__ __launch_bounds__(128) void k_edge_fwd(const float* __restrict__ x,
    const float* __restrict__ WA, const float* __restrict__ WB,
    const float* __restrict__ U, const float* __restrict__ Rr,
    float* __restrict__ aggP){
  __shared__ float sh[WPB][L*F];
  int bid = blockIdx.x;
  int g = bid & (GSP-1), bn = bid >> 2;
  int b = bn >> 7, n = bn & (NA-1);
  int t = threadIdx.x, f = t&63, wv = t>>6;
  int wvu = __builtin_amdgcn_readfirstlane(wv);   // SGPR wave index -> scalar loads
  float wa[K], wb[K];
  #pragma unroll
  for (int k=0;k<K;k++){ wa[k]=WA[k*F+f]; wb[k]=WB[k*F+f]; }
  float acc[L];
  #pragma unroll
  for (int l=0;l<L;l++) acc[l]=0.f;
  const float* xb = x + (size_t)b*NA*L*F;
  int c0 = g*(WPB*NSUB) + wvu*NSUB, c1 = min(c0+NSUB, NA-1);
  #pragma unroll 2
  for (int c=c0; c<c1; ++c){
    int e = n*(NA-1)+c;
    int j = c + (c>=n);
    size_t ge = (size_t)b*EPN + e;
    const float* Re = Rr + ge*K;
    float RA=0.f, RB=0.f;
    #pragma unroll
    for (int k=0;k<K;k++){ float rk=Re[k]; RA += rk*wa[k]; RB += rk*wb[k]; }
    float ux=U[ge*4+0], uy=U[ge*4+1], uz=U[ge*4+2];
    float Y4=SQ3*ux*uy, Y5=SQ3*uy*uz, Y6=0.5f*(3.f*uz*uz-1.f);
    float Y7=SQ3*ux*uz, Y8=0.5f*SQ3*(ux*ux-uy*uy);
    const float* xr = xb + (size_t)j*L*F + f;
    float xs0 = xr[0];
    float t1 = RA*xs0;
    acc[0] += t1 + xs0*RB;
    if (FIRST){
      acc[1] += ux*t1; acc[2] += uy*t1; acc[3] += uz*t1;
      acc[4] += Y4*t1; acc[5] += Y5*t1; acc[6] += Y6*t1;
      acc[7] += Y7*t1; acc[8] += Y8*t1;
    } else {
      acc[1] += ux*t1 + xr[1*F]*RB;
      acc[2] += uy*t1 + xr[2*F]*RB;
      acc[3] += uz*t1 + xr[3*F]*RB;
      acc[4] += Y4*t1 + xr[4*F]*RB;
      acc[5] += Y5*t1 + xr[5*F]*RB;
      acc[6] += Y6*t1 + xr[6*F]*RB;
      acc[7] += Y7*t1 + xr[7*F]*RB;
      acc[8] += Y8*t1 + xr[8*F]*RB;
    }
  }
  #pragma unroll
  for (int l=0;l<L;l++) sh[wv][l*F+f] = acc[l];
  __syncthreads();
  float* ar = aggP + (size_t)g*NNLF + (size_t)bn*L*F;
  for (int idx=t; idx<L*F; idx+=128)
    ar[idx] = sh[0][idx]+sh[1][idx];
}

// ---------------- layer node forward (4 waves, l-split, 4 slabs) --------------
__global__ __launch_bounds__(256) void k_node_fwd(const float* __restrict__ x,
    const float* __restrict__ aggP, const float* __restrict__ W1,
    const float* __restrict__ b1, const float* __restrict__ W2,
    float* __restrict__ y2out, float* __restrict__ xout){
  __shared__ float sh[L*F];
  __shared__ float yb[L*F];
  __shared__ float zb[L*F];
  int t = threadIdx.x, g = t&63, w = t>>6;
  size_t base = ((size_t)blockIdx.x)*L*F;
  for (int idx=t; idx<L*F; idx+=256){
    float s = x[base+idx];
    #pragma unroll
    for (int sl=0; sl<GSP; sl++) s += aggP[(size_t)sl*NNLF + base + idx];
    sh[idx]=s;
  }
  __syncthreads();
  for (int l=w; l<L; l+=4){
    const float* W = W1 + DEGC[l]*F*F + g;
    float s=0.f;
    for (int ff=0; ff<F; ff++) s += sh[l*F+ff]*W[(size_t)ff*F];
    if (l==0) s += b1[g];
    y2out[base+l*F+g]=s;
    yb[l*F+g]=s;
  }
  __syncthreads();
  float sv = yb[g];
  float sg = 1.f/(1.f+expf(-sv));
  for (int l=w; l<L; l+=4)
    zb[l*F+g] = (l==0)? sv*sg : yb[l*F+g]*sg;
  __syncthreads();
  for (int l=w; l<L; l+=4){
    const float* W = W2 + DEGC[l]*F*F + g;
    float s=0.f;
    for (int ff=0; ff<F; ff++) s += zb[l*F+ff]*W[(size_t)ff*F];
    xout[base+l*F+g] = x[base+l*F+g] + s;
  }
}

// ---------------- readout edge forward (2-wave, GSP=4, LDS combine) -----------
__global__ __launch_bounds__(128) void k_redge_fwd(const float* __restrict__ x2,
    const float* __restrict__ WA2, const float* __restrict__ WB2,
    const float* __restrict__ U, const float* __restrict__ Rr,
    float* __restrict__ yRp){
  __shared__ float sh[WPB][F];
  int bid = blockIdx.x;
  int g = bid & (GSP-1), bn = bid >> 2;
  int b = bn >> 7, n = bn & (NA-1);
  int t = threadIdx.x, f = t&63, wv = t>>6;
  int wvu = __builtin_amdgcn_readfirstlane(wv);
  float wa[K], wb[K];
  #pragma unroll
  for (int k=0;k<K;k++){ wa[k]=WA2[k*F+f]; wb[k]=WB2[k*F+f]; }
  float acc=0.f;
  const float* xb = x2 + (size_t)b*NA*L*F;
  int c0 = g*(WPB*NSUB) + wvu*NSUB, c1 = min(c0+NSUB, NA-1);
  #pragma unroll 2
  for (int c=c0; c<c1; ++c){
    int e = n*(NA-1)+c;
    int j = c + (c>=n);
    size_t ge = (size_t)b*EPN + e;
    const float* Re = Rr + ge*K;
    float RA=0.f, RB=0.f;
    #pragma unroll
    for (int k=0;k<K;k++){ float rk=Re[k]; RA += rk*wa[k]; RB += rk*wb[k]; }
    float ux=U[ge*4+0], uy=U[ge*4+1], uz=U[ge*4+2];
    const float* xr = xb + (size_t)j*L*F + f;
    float xs0 = xr[0];
    float T = xs0
            + ux*xr[1*F] + uy*xr[2*F] + uz*xr[3*F]
            + (SQ3*ux*uy)*xr[4*F] + (SQ3*uy*uz)*xr[5*F]
            + (0.5f*(3.f*uz*uz-1.f))*xr[6*F]
            + (SQ3*ux*uz)*xr[7*F] + (0.5f*SQ3*(ux*ux-uy*uy))*xr[8*F];
    acc += RA*xs0 + RB*T;
  }
  sh[wv][f]=acc;
  __syncthreads();
  if (t < F)
    yRp[(size_t)g*BNF + (size_t)bn*F + t] = sh[0][t]+sh[1][t];
}

// ---------------- readout node forward (4 waves, ff-split, 4 slabs) -----------
__global__ __launch_bounds__(256) void k_rnode_fwd(const int* __restrict__ z,
    const float* __restrict__ x2, const float* __restrict__ yRp,
    const float* __restrict__ W1s, const float* __restrict__ b1s,
    const float* __restrict__ W2s, const float* __restrict__ wout,
    const float* __restrict__ ebias, float* __restrict__ pW, float* Eout){
  __shared__ float sh[F];
  __shared__ float part[4][F];
  int t = threadIdx.x, g = t&63, w = t>>6;
  int bnn = blockIdx.x;
  int b = bnn >> 7;
  size_t base = (size_t)bnn*L*F;
  size_t nb   = (size_t)bnn*F;
  if (t < F){
    float s = x2[base+t];
    #pragma unroll
    for (int sl=0; sl<GSP; sl++) s += yRp[(size_t)sl*BNF + nb + t];
    sh[t]=s;
  }
  __syncthreads();
  float pp=0.f;
  for (int ff=w*16; ff<w*16+16; ff++) pp += sh[ff]*W1s[(size_t)ff*F+g];
  part[w][g]=pp;
  __syncthreads();
  float p = part[0][g]+part[1][g]+part[2][g]+part[3][g] + b1s[g];
  if (w==0) pW[nb+g]=p;
  float sp = p/(1.f+expf(-p));
  __syncthreads();
  if (w==0) sh[g]=sp;
  __syncthreads();
  float h=0.f;
  for (int ff=w*16; ff<w*16+16; ff++) h += sh[ff]*W2s[(size_t)ff*F+g];
  part[w][g]=h;
  __syncthreads();
  if (w==0){
    float h2 = part[0][g]+part[1][g]+part[2][g]+part[3][g];
    float x0v = x2[base+g];
    float en = wred((x0v+h2)*wout[g]);
    if (g==0) atomicAdd(Eout+b, en + ebias[z[bnn]]);
  }
}

// ---------------- readout node backward (4 waves, ff-split) -------------------
__global__ __launch_bounds__(256) void k_rnode_bwd(const float* __restrict__ pW,
    const float* __restrict__ dsp, const float* __restrict__ W1sT,
    const float* __restrict__ wout, float* __restrict__ dyR, float* __restrict__ dxA){
  __shared__ float sh[F];
  __shared__ float part[4][F];
  int t = threadIdx.x, g = t&63, w = t>>6;
  size_t nb = (size_t)blockIdx.x*F;
  size_t base = (size_t)blockIdx.x*L*F;
  if (t < F){
    float p  = pW[nb+t];
    float sgm = 1.f/(1.f+expf(-p));
    sh[t] = dsp[t]*sgm*(1.f + p*(1.f-sgm));
  }
  __syncthreads();
  float s=0.f;
  for (int ff=w*16; ff<w*16+16; ff++) s += sh[ff]*W1sT[(size_t)ff*F+g];
  part[w][g]=s;
  __syncthreads();
  if (w==0){
    float dh1 = part[0][g]+part[1][g]+part[2][g]+part[3][g];
    dyR[nb+g]=dh1;
    dxA[base+g] = wout[g]+dh1;
  }
  for (int idx=t; idx<(L-1)*F; idx+=256) dxA[base+F+idx]=0.f;
}

// ---------------- readout edge backward (2-wave, GSP=4, LDS combine) ----------
__global__ __launch_bounds__(128) void k_redge_bwd(const float* __restrict__ x2,
    const float* __restrict__ WA2, const float* __restrict__ WB2,
    const float* __restrict__ U, const float* __restrict__ Rr,
    const float* __restrict__ Rp, const float* __restrict__ dyR,
    float* __restrict__ partP, float* Fout){
  __shared__ float sh[WPB][L*F];
  __shared__ float shS[WPB][4];
  int bid = blockIdx.x;
  int g = bid & (GSP-1), bn = bid >> 2;
  int b = bn >> 7, j = bn & (NA-1);
  int t = threadIdx.x, f = t&63, wv = t>>6, m = f&3;
  int wvu = __builtin_amdgcn_readfirstlane(wv);
  float wa[K], wb[K];
  #pragma unroll
  for (int k=0;k<K;k++){ wa[k]=WA2[k*F+f]; wb[k]=WB2[k*F+f]; }
  size_t xbase = ((size_t)bn)*L*F;
  float xs[L];
  #pragma unroll
  for (int l=0;l<L;l++) xs[l]=x2[xbase+l*F+f];
  float acc[L];
  #pragma unroll
  for (int l=0;l<L;l++) acc[l]=0.f;
  float sdd=0.f;
  int i0 = g*(WPB*NSUB) + wvu*NSUB, i1 = min(i0+NSUB, NA-1);
  for (int ii=i0; ii<i1; ++ii){
    int i = ii + (ii>=j);
    int c = (j<i)? j : j-1;
    size_t ge = (size_t)b*EPN + i*(NA-1)+c;
    float gv = dyR[(size_t)(b*NA+i)*F+f];
    const float* Re = Rr + ge*K;
    const float* Pe = Rp + ge*K;
    float RA=0.f,RB=0.f,PA=0.f,PB=0.f;
    #pragma unroll
    for (int k=0;k<K;k++){ float rk=Re[k],pk=Pe[k];
      RA+=rk*wa[k]; RB+=rk*wb[k]; PA+=pk*wa[k]; PB+=pk*wb[k]; }
    float ux=U[ge*4+0], uy=U[ge*4+1], uz=U[ge*4+2], ir=U[ge*4+3];
    float Y4=SQ3*ux*uy, Y5=SQ3*uy*uz, Y6=0.5f*(3.f*uz*uz-1.f);
    float Y7=SQ3*ux*uz, Y8=0.5f*SQ3*(ux*ux-uy*uy);
    float T = xs[0] + ux*xs[1]+uy*xs[2]+uz*xs[3]
            + Y4*xs[4]+Y5*xs[5]+Y6*xs[6]+Y7*xs[7]+Y8*xs[8];
    float X0 = xs[1] + SQ3*(uy*xs[4]+uz*xs[7]+ux*xs[8]);
    float X1 = xs[2] + SQ3*(ux*xs[4]+uz*xs[5]-uy*xs[8]);
    float X2 = xs[3] + SQ3*(uy*xs[5]+ux*xs[7]) + 3.f*uz*xs[6];
    acc[0] += gv*(RA+RB);
    acc[1] += gv*ux*RB; acc[2] += gv*uy*RB; acc[3] += gv*uz*RB;
    acc[4] += gv*Y4*RB; acc[5] += gv*Y5*RB; acc[6] += gv*Y6*RB;
    acc[7] += gv*Y7*RB; acc[8] += gv*Y8*RB;
    float gRB = gv*RB;
    float dotX = ux*X0 + uy*X1 + uz*X2;
    float v3 = gv*(xs[0]*PA + T*PB) - gRB*dotX*ir;
    float r4 = qreduce(gRB*X0, gRB*X1, gRB*X2, v3, f);
    float SR = __shfl(r4, f|3, 64);
    float um = (m==0)?ux : (m==1)?uy : (m==2)?uz : 0.f;
    float dd = r4*ir + SR*um;
    if (f<3) atomicAdd(&Fout[(size_t)(b*NA+i)*3+f], dd);
    sdd += dd;
  }
  #pragma unroll
  for (int l=0;l<L;l++) sh[wv][l*F+f]=acc[l];
  if (f<3) shS[wv][f]=sdd;
  __syncthreads();
  float* ar = partP + (size_t)g*NNLF + xbase;
  for (int idx=t; idx<L*F; idx+=128)
    ar[idx] = sh[0][idx]+sh[1][idx];
  if (t<3)
    atomicAdd(&Fout[(size_t)bn*3+t], -(shS[0][t]+shS[1][t]));
}

// ---------------- layer node backward (4 waves, l-split, 4 slabs) -------------
template<bool WDX>
__global__ __launch_bounds__(256) void k_node_bwd(const float* __restrict__ dxIn,
    const float* __restrict__ partP, const float* __restrict__ y2W,
    const float* __restrict__ W1T, const float* __restrict__ W2T,
    float* __restrict__ dagg, float* __restrict__ dxOut){
  __shared__ float A[L*F];
  __shared__ float D3[L*F];
  __shared__ float Bb[L*F];
  __shared__ float prt[4][F];
  int t = threadIdx.x, g = t&63, w = t>>6;
  size_t base = ((size_t)blockIdx.x)*L*F;
  for (int idx=t; idx<L*F; idx+=256){
    float s = dxIn[base+idx];
    #pragma unroll
    for (int sl=0; sl<GSP; sl++) s += partP[(size_t)sl*NNLF + base + idx];
    A[idx]=s;
  }
  __syncthreads();
  float pc=0.f;
  for (int l=w; l<L; l+=4){
    const float* W = W2T + DEGC[l]*F*F + g;
    float s=0.f;
    for (int ff=0; ff<F; ff++) s += A[l*F+ff]*W[(size_t)ff*F];
    D3[l*F+g]=s;
    if (l>0) pc += s * y2W[base+l*F+g];
  }
  prt[w][g]=pc;
  __syncthreads();
  float sv = y2W[base+g];
  float sg = 1.f/(1.f+expf(-sv));
  for (int l=w; l<L; l+=4){
    float v;
    if (l==0){
      float sum = prt[0][g]+prt[1][g]+prt[2][g]+prt[3][g];
      v = D3[g]*sg*(1.f+sv*(1.f-sg)) + sum*sg*(1.f-sg);
    } else {
      v = D3[l*F+g]*sg;
    }
    Bb[l*F+g]=v;
  }
  __syncthreads();
  for (int l=w; l<L; l+=4){
    const float* W = W1T + DEGC[l]*F*F + g;
    float s=0.f;
    for (int ff=0; ff<F; ff++) s += Bb[l*F+ff]*W[(size_t)ff*F];
    dagg[base+l*F+g]=s;
    if (WDX) dxOut[base+l*F+g] = A[l*F+g] + s;
  }
}

// ---------------- layer edge backward (2-wave, GSP=4, LDS combine) ------------
template<bool WDX, bool FIRST>
__global__ __launch_bounds__(128) void k_edge_bwd(const float* __restrict__ xI,
    const float* __restrict__ WA, const float* __restrict__ WB,
    const float* __restrict__ U, const float* __restrict__ Rr,
    const float* __restrict__ Rp, const float* __restrict__ dagg,
    float* __restrict__ partP, float* Fout){
  __shared__ float sh[WPB][L*F];
  __shared__ float shS[WPB][4];
  int bid = blockIdx.x;
  int g = bid & (GSP-1), bn = bid >> 2;
  int b = bn >> 7, j = bn & (NA-1);
  int t = threadIdx.x, f = t&63, wv = t>>6, m = f&3;
  int wvu = __builtin_amdgcn_readfirstlane(wv);
  float wa[K], wb[K];
  #pragma unroll
  for (int k=0;k<K;k++){ wa[k]=WA[k*F+f]; wb[k]=WB[k*F+f]; }
  size_t xbase = ((size_t)bn)*L*F;
  float xs[L];
  xs[0] = xI[xbase+f];
  #pragma unroll
  for (int l=1;l<L;l++) xs[l] = FIRST ? 0.f : xI[xbase+l*F+f];
  float acc[L]; float acc0=0.f;
  #pragma unroll
  for (int l=0;l<L;l++) acc[l]=0.f;
  float sdd=0.f;
  int i0 = g*(WPB*NSUB) + wvu*NSUB, i1 = min(i0+NSUB, NA-1);
  for (int ii=i0; ii<i1; ++ii){
    int i = ii + (ii>=j);
    int c = (j<i)? j : j-1;
    size_t ge = (size_t)b*EPN + i*(NA-1)+c;
    const float* gr = dagg + ((size_t)(b*NA+i))*L*F + f;
    float gl[L];
    #pragma unroll
    for (int l=0;l<L;l++) gl[l]=gr[l*F];
    const float* Re = Rr + ge*K;
    const float* Pe = Rp + ge*K;
    float RA=0.f,RB=0.f,PA=0.f,PB=0.f;
    #pragma unroll
    for (int k=0;k<K;k++){ float rk=Re[k],pk=Pe[k];
      RA+=rk*wa[k]; RB+=rk*wb[k]; PA+=pk*wa[k]; PB+=pk*wb[k]; }
    float ux=U[ge*4+0], uy=U[ge*4+1], uz=U[ge*4+2], ir=U[ge*4+3];
    float Y4=SQ3*ux*uy, Y5=SQ3*uy*uz, Y6=0.5f*(3.f*uz*uz-1.f);
    float Y7=SQ3*ux*uz, Y8=0.5f*SQ3*(ux*ux-uy*uy);
    float gy = gl[0] + gl[1]*ux+gl[2]*uy+gl[3]*uz
             + gl[4]*Y4+gl[5]*Y5+gl[6]*Y6+gl[7]*Y7+gl[8]*Y8;
    float gx;
    if (FIRST){
      gx = gl[0]*xs[0];
    } else {
      gx = 0.f;
      #pragma unroll
      for (int l=0;l<L;l++) gx += gl[l]*xs[l];
    }
    float G0 = gl[1] + SQ3*(uy*gl[4]+uz*gl[7]+ux*gl[8]);
    float G1 = gl[2] + SQ3*(ux*gl[4]+uz*gl[5]-uy*gl[8]);
    float G2 = gl[3] + SQ3*(uy*gl[5]+ux*gl[7]) + 3.f*uz*gl[6];
    if (WDX){
      acc0 += gy*RA;
      #pragma unroll
      for (int l=0;l<L;l++) acc[l] += gl[l]*RB;
    }
    float cm = RA*xs[0];
    float dotG = ux*G0 + uy*G1 + uz*G2;
    float v3 = gy*xs[0]*PA + gx*PB - cm*dotG*ir;
    float r4 = qreduce(cm*G0, cm*G1, cm*G2, v3, f);
    float SR = __shfl(r4, f|3, 64);
    float um = (m==0)?ux : (m==1)?uy : (m==2)?uz : 0.f;
    float dd = r4*ir + SR*um;
    if (f<3) atomicAdd(&Fout[(size_t)(b*NA+i)*3+f], dd);
    sdd += dd;
  }
  if (WDX){
    sh[wv][f] = acc0 + acc[0];
    #pragma unroll
    for (int l=1;l<L;l++) sh[wv][l*F+f] = acc[l];
  }
  if (f<3) shS[wv][f]=sdd;
  __syncthreads();
  if (WDX){
    float* ar = partP + (size_t)g*NNLF + xbase;
    for (int idx=t; idx<L*F; idx+=128)
      ar[idx] = sh[0][idx]+sh[1][idx];
  }
  if (t<3)
    atomicAdd(&Fout[(size_t)bn*3+t], -(shS[0][t]+shS[1][t]));
}

} // anonymous namespace

extern "C" void kernel_launch(void* const* d_in, const int* in_sizes, int n_in,
                              void* d_out, int out_size, void* d_ws, size_t ws_size,
                              hipStream_t stream){
  (void)in_sizes; (void)n_in; (void)out_size; (void)ws_size;
  const int*   z     = (const int*)  d_in[0];
  const float* pos   = (const float*)d_in[1];
  const float* emb   = (const float*)d_in[2];
  const float* WA    = (const float*)d_in[3];
  const float* WB    = (const float*)d_in[4];
  const float* W1    = (const float*)d_in[5];
  const float* b1    = (const float*)d_in[6];
  const float* W2    = (const float*)d_in[7];
  const float* W1s   = (const float*)d_in[8];
  const float* b1s   = (const float*)d_in[9];
  const float* W2s   = (const float*)d_in[10];
  const float* wout  = (const float*)d_in[11];
  const float* ebias = (const float*)d_in[12];
  const int*   dsti  = (const int*)  d_in[13];
  const int*   srci  = (const int*)  d_in[14];

  float* w    = (float*)d_ws;
  float* U    = w;                          // BE*4
  float* Rr   = U    + (size_t)BE*4;        // BE*16
  float* Rp   = Rr   + (size_t)BE*16;       // BE*16
  float* x0   = Rp   + (size_t)BE*16;       // NNLF
  float* x1   = x0   + NNLF;                // NNLF
  float* x2   = x1   + NNLF;                // NNLF
  float* y2b  = x2   + NNLF;                // 2*NNLF
  float* part = y2b  + 2*(size_t)NNLF;      // GSP*NNLF
  float* yRp  = part + (size_t)GSP*NNLF;    // GSP*BNF
  float* pW   = yRp  + (size_t)GSP*BNF;     // BNF
  float* dyR  = pW   + BNF;                 // BNF
  float* dxA  = dyR  + BNF;                 // NNLF
  float* dxO  = dxA  + NNLF;                // NNLF
  float* dagg = dxO  + NNLF;                // NNLF
  float* W1T  = dagg + NNLF;                // 6*F*F
  float* W2T  = W1T  + 6*F*F;               // 6*F*F
  float* W1sT = W2T  + 6*F*F;               // F*F
  float* dspv = W1sT + F*F;                 // F

  float* Eout = (float*)d_out;
  float* Fout = Eout + NB;

  dim3 bn(NB*NA);
  dim3 be(NB*NA*GSP);

  k_prep  <<<126, 256, 0, stream>>>(W1, W2, W1s, W2s, wout, W1T, W2T, W1sT, dspv, Eout);
  k_geom  <<<(BE+255)/256, 256, 0, stream>>>(pos, dsti, srci, U, Rr, Rp);
  k_init_x<<<bn, 64, 0, stream>>>(z, emb, x0);

  // layer 0
  k_edge_fwd<true ><<<be, 128, 0, stream>>>(x0, WA,     WB,     U, Rr, part);
  k_node_fwd<<<bn, 256, 0, stream>>>(x0, part, W1,       b1,   W2,       y2b,      x1);
  // layer 1
  k_edge_fwd<false><<<be, 128, 0, stream>>>(x1, WA+K*F, WB+K*F, U, Rr, part);
  k_node_fwd<<<bn, 256, 0, stream>>>(x1, part, W1+3*F*F, b1+F, W2+3*F*F, y2b+NNLF, x2);
  // readout
  k_redge_fwd<<<be, 128, 0, stream>>>(x2, WA+2*K*F, WB+2*K*F, U, Rr, yRp);
  k_rnode_fwd<<<bn, 256, 0, stream>>>(z, x2, yRp, W1s, b1s, W2s, wout, ebias, pW, Eout);

  // backward
  k_rnode_bwd<<<bn, 256, 0, stream>>>(pW, dspv, W1sT, wout, dyR, dxA);
  k_redge_bwd<<<be, 128, 0, stream>>>(x2, WA+2*K*F, WB+2*K*F, U, Rr, Rp, dyR, part, Fout);
  // layer 1 bwd
  k_node_bwd<true ><<<bn, 256, 0, stream>>>(dxA, part, y2b+NNLF, W1T+3*F*F, W2T+3*F*F, dagg, dxO);
  k_edge_bwd<true ,false><<<be, 128, 0, stream>>>(x1, WA+K*F, WB+K*F, U, Rr, Rp, dagg, part, Fout);
  // layer 0 bwd
  k_node_bwd<false><<<bn, 256, 0, stream>>>(dxO, part, y2b, W1T, W2T, dagg, nullptr);
  k_edge_bwd<false,true ><<<be, 128, 0, stream>>>(x0, WA, WB, U, Rr, Rp, dagg, nullptr, Fout);
}

// Round 13
// 398.818 us; speedup vs baseline: 1.2935x; 1.0387x over previous
//
#include <hip/hip_runtime.h>
#include <math.h>

namespace {

constexpr int F   = 64;            // FEAT
constexpr int NA  = 128;           // atoms
constexpr int NB  = 8;             // batch
constexpr int EPN = NA*(NA-1);     // 16256 edges per sample
constexpr int K   = 16;            // radial basis
constexpr int L   = 9;             // irreps
constexpr int BE  = NB*EPN;        // 130048 total edges
constexpr int NNLF= NB*NA*L*F;     // 589824
constexpr int BNF = NB*NA*F;      // 65536
constexpr int GSP = 4;             // neighbor-split factor (grid parallelism)
constexpr int NSUB= 32;            // neighbors per block (4*32 >= 127)
constexpr float SQ3 = 1.7320508075688772f;

__device__ __constant__ float BINOM[16] = {1.f,15.f,105.f,455.f,1365.f,3003.f,5005.f,6435.f,
                                           6435.f,5005.f,3003.f,1365.f,455.f,105.f,15.f,1.f};
__device__ __constant__ int DEGC[9] = {0,1,1,1,2,2,2,2,2};

__device__ inline float wred(float v){
  #pragma unroll
  for (int o=32;o>0;o>>=1) v += __shfl_xor(v, o, 64);
  return v;
}

// packed 4-value wave64 reduction: returns on every lane the total of v_{lane&3}
__device__ inline float qreduce(float v0, float v1, float v2, float v3, int lane){
  float a = ((lane&1)? v1 : v0) + __shfl_xor(((lane&1)? v0 : v1), 1, 64);
  float b = ((lane&1)? v3 : v2) + __shfl_xor(((lane&1)? v2 : v3), 1, 64);
  float r = ((lane&2)? b : a) + __shfl_xor(((lane&2)? a : b), 2, 64);
  r += __shfl_xor(r, 4, 64);
  r += __shfl_xor(r, 8, 64);
  r += __shfl_xor(r,16, 64);
  r += __shfl_xor(r,32, 64);
  return r;
}

// ---------------- prep: transposes, dsp = W2s@wout, zero d_out ----------------
__global__ void k_prep(const float* W1, const float* W2, const float* W1s,
                       const float* W2s, const float* wout,
                       float* W1T, float* W2T, float* W1sT, float* dsp,
                       float* outbuf){
  int idx = blockIdx.x*256 + threadIdx.x;
  if (idx < 6*F*F){
    int rem = idx % (F*F); int m = idx/(F*F); int g = rem/F, f = rem%F;
    W1T[idx] = W1[(m*F+f)*F+g];
    W2T[idx] = W2[(m*F+f)*F+g];
  } else if (idx < 6*F*F + F*F){
    int rem = idx - 6*F*F; int g = rem/F, f = rem%F;
    W1sT[rem] = W1s[f*F+g];
  } else if (idx < 6*F*F + F*F + F){
    int f = idx - 6*F*F - F*F;
    float s=0.f;
    for (int g=0; g<F; g++) s += W2s[f*F+g]*wout[g];
    dsp[f]=s;
  } else if (idx < 6*F*F + F*F + F + NB + NB*NA*3){
    outbuf[idx - (6*F*F + F*F + F)] = 0.f;   // Eout + Fout zero (atomic targets)
  }
}

// ---------------- per-edge geometry: u, 1/r, R=rad*cut, R'=d(rad*cut)/dr ------
__global__ void k_geom(const float* __restrict__ pos, const int* __restrict__ dsti,
                       const int* __restrict__ srci,
                       float* __restrict__ U, float* __restrict__ Rr,
                       float* __restrict__ Rp){
  int idx = blockIdx.x*256 + threadIdx.x;
  if (idx >= BE) return;
  int b = idx / EPN, e = idx % EPN;
  int d = dsti[e], s = srci[e];
  const float* pb = pos + (size_t)b*NA*3;
  float dx = pb[s*3+0]-pb[d*3+0];
  float dy = pb[s*3+1]-pb[d*3+1];
  float dz = pb[s*3+2]-pb[d*3+2];
  float ss = dx*dx+dy*dy+dz*dz + 1e-12f;
  float r  = sqrtf(ss);
  float ir = 1.f/r;
  U[(size_t)idx*4+0]=dx*ir; U[(size_t)idx*4+1]=dy*ir;
  U[(size_t)idx*4+2]=dz*ir; U[(size_t)idx*4+3]=ir;
  float w = 1.f/(1.f+r), v = 1.f - w;
  float wp[16], vp[16];
  wp[0]=1.f; vp[0]=1.f;
  #pragma unroll
  for (int k=1;k<16;k++){ wp[k]=wp[k-1]*w; vp[k]=vp[k-1]*v; }
  float t = (r*0.2f)*(r*0.2f);
  float cut=0.f, dcut=0.f;
  if (t < 1.f){
    float e1 = 1.f - t;
    float m  = fmaxf(e1, 1e-12f);
    cut = expf(1.f - 1.f/m);
    if (e1 > 1e-12f) dcut = -cut/(e1*e1) * (2.f*r*0.04f);
  }
  float nww = -w*w;
  #pragma unroll
  for (int k=0;k<16;k++){
    float rad = BINOM[k]*wp[k]*vp[15-k];
    float t1 = (k>0)  ? (float)k      * wp[k-1]*vp[15-k] : 0.f;
    float t2 = (k<15) ? (float)(15-k) * wp[k]  *vp[14-k] : 0.f;
    float dradr = BINOM[k]*(t1-t2)*nww;
    Rr[(size_t)idx*16+k] = rad*cut;
    Rp[(size_t)idx*16+k] = dradr*cut + rad*dcut;
  }
}

// ---------------- x init ------------------------------------------------------
__global__ void k_init_x(const int* __restrict__ z, const float* __restrict__ embed,
                         float* __restrict__ x0){
  int b = blockIdx.x / NA, n = blockIdx.x % NA, f = threadIdx.x;
  int zi = z[b*NA+n];
  float* row = x0 + ((size_t)(b*NA+n))*L*F;
  row[f] = embed[(size_t)zi*F+f];
  #pragma unroll
  for (int l=1;l<L;l++) row[l*F+f]=0.f;
}

// ---------------- layer edge forward (1-wave blocks, neighbor-split) ----------
template<bool FIRST>
__global__ __launch_bounds__(64,4) void k_edge_fwd(const float* __restrict__ x,
    const float* __restrict__ WA, const float* __restrict__ WB,
    const float* __restrict__ U, const float* __restrict__ Rr,
    float* __restrict__ aggP){
  int bid = blockIdx.x;
  int g = bid & (GSP-1), bn = bid >> 2;
  int b = bn >> 7, n = bn & (NA-1);
  int f = threadIdx.x;
  float wa[K], wb[K];
  #pragma unroll
  for (int k=0;k<K;k++){ wa[k]=WA[k*F+f]; wb[k]=WB[k*F+f]; }
  float acc[L];
  #pragma unroll
  for (int l=0;l<L;l++) acc[l]=0.f;
  const float* xb = x + (size_t)b*NA*L*F;
  int c0 = g*NSUB, c1 = min(c0+NSUB, NA-1);
  #pragma unroll 2
  for (int c=c0; c<c1; ++c){
    int e = n*(NA-1)+c;
    int j = c + (c>=n);
    size_t ge = (size_t)b*EPN + e;
    const float* Re = Rr + ge*K;
    float RA=0.f, RB=0.f;
    #pragma unroll
    for (int k=0;k<K;k++){ float rk=Re[k]; RA += rk*wa[k]; RB += rk*wb[k]; }
    float ux=U[ge*4+0], uy=U[ge*4+1], uz=U[ge*4+2];
    float Y4=SQ3*ux*uy, Y5=SQ3*uy*uz, Y6=0.5f*(3.f*uz*uz-1.f);
    float Y7=SQ3*ux*uz, Y8=0.5f*SQ3*(ux*ux-uy*uy);
    const float* xr = xb + (size_t)j*L*F + f;
    float xs0 = xr[0];
    float t1 = RA*xs0;
    acc[0] += t1 + xs0*RB;
    if (FIRST){
      acc[1] += ux*t1; acc[2] += uy*t1; acc[3] += uz*t1;
      acc[4] += Y4*t1; acc[5] += Y5*t1; acc[6] += Y6*t1;
      acc[7] += Y7*t1; acc[8] += Y8*t1;
    } else {
      acc[1] += ux*t1 + xr[1*F]*RB;
      acc[2] += uy*t1 + xr[2*F]*RB;
      acc[3] += uz*t1 + xr[3*F]*RB;
      acc[4] += Y4*t1 + xr[4*F]*RB;
      acc[5] += Y5*t1 + xr[5*F]*RB;
      acc[6] += Y6*t1 + xr[6*F]*RB;
      acc[7] += Y7*t1 + xr[7*F]*RB;
      acc[8] += Y8*t1 + xr[8*F]*RB;
    }
  }
  float* ar = aggP + (size_t)g*NNLF + (size_t)bn*L*F + f;
  #pragma unroll
  for (int l=0;l<L;l++) ar[l*F] = acc[l];
}

// ---------------- layer node forward (4 waves, l-split, 4 slabs) --------------
__global__ __launch_bounds__(256) void k_node_fwd(const float* __restrict__ x,
    const float* __restrict__ aggP, const float* __restrict__ W1,
    const float* __restrict__ b1, const float* __restrict__ W2,
    float* __restrict__ y2out, float* __restrict__ xout){
  __shared__ float sh[L*F];
  __shared__ float yb[L*F];
  __shared__ float zb[L*F];
  int t = threadIdx.x, g = t&63, w = t>>6;
  size_t base = ((size_t)blockIdx.x)*L*F;
  for (int idx=t; idx<L*F; idx+=256){
    float s = x[base+idx];
    #pragma unroll
    for (int sl=0; sl<GSP; sl++) s += aggP[(size_t)sl*NNLF + base + idx];
    sh[idx]=s;
  }
  __syncthreads();
  for (int l=w; l<L; l+=4){
    const float* W = W1 + DEGC[l]*F*F + g;
    float s=0.f;
    for (int ff=0; ff<F; ff++) s += sh[l*F+ff]*W[(size_t)ff*F];
    if (l==0) s += b1[g];
    y2out[base+l*F+g]=s;
    yb[l*F+g]=s;
  }
  __syncthreads();
  float sv = yb[g];
  float sg = 1.f/(1.f+expf(-sv));
  for (int l=w; l<L; l+=4)
    zb[l*F+g] = (l==0)? sv*sg : yb[l*F+g]*sg;
  __syncthreads();
  for (int l=w; l<L; l+=4){
    const float* W = W2 + DEGC[l]*F*F + g;
    float s=0.f;
    for (int ff=0; ff<F; ff++) s += zb[l*F+ff]*W[(size_t)ff*F];
    xout[base+l*F+g] = x[base+l*F+g] + s;
  }
}

// ---------------- readout edge forward (1-wave, split) ------------------------
__global__ __launch_bounds__(64,4) void k_redge_fwd(const float* __restrict__ x2,
    const float* __restrict__ WA2, const float* __restrict__ WB2,
    const float* __restrict__ U, const float* __restrict__ Rr,
    float* __restrict__ yRp){
  int bid = blockIdx.x;
  int g = bid & (GSP-1), bn = bid >> 2;
  int b = bn >> 7, n = bn & (NA-1);
  int f = threadIdx.x;
  float wa[K], wb[K];
  #pragma unroll
  for (int k=0;k<K;k++){ wa[k]=WA2[k*F+f]; wb[k]=WB2[k*F+f]; }
  float acc=0.f;
  const float* xb = x2 + (size_t)b*NA*L*F;
  int c0 = g*NSUB, c1 = min(c0+NSUB, NA-1);
  #pragma unroll 2
  for (int c=c0; c<c1; ++c){
    int e = n*(NA-1)+c;
    int j = c + (c>=n);
    size_t ge = (size_t)b*EPN + e;
    const float* Re = Rr + ge*K;
    float RA=0.f, RB=0.f;
    #pragma unroll
    for (int k=0;k<K;k++){ float rk=Re[k]; RA += rk*wa[k]; RB += rk*wb[k]; }
    float ux=U[ge*4+0], uy=U[ge*4+1], uz=U[ge*4+2];
    const float* xr = xb + (size_t)j*L*F + f;
    float xs0 = xr[0];
    float T = xs0
            + ux*xr[1*F] + uy*xr[2*F] + uz*xr[3*F]
            + (SQ3*ux*uy)*xr[4*F] + (SQ3*uy*uz)*xr[5*F]
            + (0.5f*(3.f*uz*uz-1.f))*xr[6*F]
            + (SQ3*ux*uz)*xr[7*F] + (0.5f*SQ3*(ux*ux-uy*uy))*xr[8*F];
    acc += RA*xs0 + RB*T;
  }
  yRp[(size_t)g*BNF + (size_t)bn*F + f] = acc;
}

// ---------------- readout node forward (4 waves, ff-split, 4 slabs) -----------
__global__ __launch_bounds__(256) void k_rnode_fwd(const int* __restrict__ z,
    const float* __restrict__ x2, const float* __restrict__ yRp,
    const float* __restrict__ W1s, const float* __restrict__ b1s,
    const float* __restrict__ W2s, const float* __restrict__ wout,
    const float* __restrict__ ebias, float* __restrict__ pW, float* Eout){
  __shared__ float sh[F];
  __shared__ float part[4][F];
  int t = threadIdx.x, g = t&63, w = t>>6;
  int bnn = blockIdx.x;
  int b = bnn >> 7;
  size_t base = (size_t)bnn*L*F;
  size_t nb   = (size_t)bnn*F;
  if (t < F){
    float s = x2[base+t];
    #pragma unroll
    for (int sl=0; sl<GSP; sl++) s += yRp[(size_t)sl*BNF + nb + t];
    sh[t]=s;
  }
  __syncthreads();
  float pp=0.f;
  for (int ff=w*16; ff<w*16+16; ff++) pp += sh[ff]*W1s[(size_t)ff*F+g];
  part[w][g]=pp;
  __syncthreads();
  float p = part[0][g]+part[1][g]+part[2][g]+part[3][g] + b1s[g];
  if (w==0) pW[nb+g]=p;
  float sp = p/(1.f+expf(-p));
  __syncthreads();
  if (w==0) sh[g]=sp;
  __syncthreads();
  float h=0.f;
  for (int ff=w*16; ff<w*16+16; ff++) h += sh[ff]*W2s[(size_t)ff*F+g];
  part[w][g]=h;
  __syncthreads();
  if (w==0){
    float h2 = part[0][g]+part[1][g]+part[2][g]+part[3][g];
    float x0v = x2[base+g];
    float en = wred((x0v+h2)*wout[g]);
    if (g==0) atomicAdd(Eout+b, en + ebias[z[bnn]]);
  }
}

// ---------------- readout node backward (4 waves, ff-split) -------------------
__global__ __launch_bounds__(256) void k_rnode_bwd(const float* __restrict__ pW,
    const float* __restrict__ dsp, const float* __restrict__ W1sT,
    const float* __restrict__ wout, float* __restrict__ dyR, float* __restrict__ dxA){
  __shared__ float sh[F];
  __shared__ float part[4][F];
  int t = threadIdx.x, g = t&63, w = t>>6;
  size_t nb = (size_t)blockIdx.x*F;
  size_t base = (size_t)blockIdx.x*L*F;
  if (t < F){
    float p  = pW[nb+t];
    float sgm = 1.f/(1.f+expf(-p));
    sh[t] = dsp[t]*sgm*(1.f + p*(1.f-sgm));
  }
  __syncthreads();
  float s=0.f;
  for (int ff=w*16; ff<w*16+16; ff++) s += sh[ff]*W1sT[(size_t)ff*F+g];
  part[w][g]=s;
  __syncthreads();
  if (w==0){
    float dh1 = part[0][g]+part[1][g]+part[2][g]+part[3][g];
    dyR[nb+g]=dh1;
    dxA[base+g] = wout[g]+dh1;
  }
  for (int idx=t; idx<(L-1)*F; idx+=256) dxA[base+F+idx]=0.f;
}

// ---------------- readout edge backward (1-wave, split, force atomics) --------
__global__ __launch_bounds__(64,4) void k_redge_bwd(const float* __restrict__ x2,
    const float* __restrict__ WA2, const float* __restrict__ WB2,
    const float* __restrict__ U, const float* __restrict__ Rr,
    const float* __restrict__ Rp, const float* __restrict__ dyR,
    float* __restrict__ partP, float* Fout){
  int bid = blockIdx.x;
  int g = bid & (GSP-1), bn = bid >> 2;
  int b = bn >> 7, j = bn & (NA-1);
  int f = threadIdx.x, m = f & 3;
  float wa[K], wb[K];
  #pragma unroll
  for (int k=0;k<K;k++){ wa[k]=WA2[k*F+f]; wb[k]=WB2[k*F+f]; }
  size_t xbase = ((size_t)bn)*L*F;
  float xs[L];
  #pragma unroll
  for (int l=0;l<L;l++) xs[l]=x2[xbase+l*F+f];
  float acc[L];
  #pragma unroll
  for (int l=0;l<L;l++) acc[l]=0.f;
  float sdd=0.f;
  int i0 = g*NSUB, i1 = min(i0+NSUB, NA-1);
  #pragma unroll 2
  for (int ii=i0; ii<i1; ++ii){
    int i = ii + (ii>=j);
    int c = (j<i)? j : j-1;
    size_t ge = (size_t)b*EPN + i*(NA-1)+c;
    float gv = dyR[(size_t)(b*NA+i)*F+f];
    const float* Re = Rr + ge*K;
    const float* Pe = Rp + ge*K;
    float RA=0.f,RB=0.f,PA=0.f,PB=0.f;
    #pragma unroll
    for (int k=0;k<K;k++){ float rk=Re[k],pk=Pe[k];
      RA+=rk*wa[k]; RB+=rk*wb[k]; PA+=pk*wa[k]; PB+=pk*wb[k]; }
    float ux=U[ge*4+0], uy=U[ge*4+1], uz=U[ge*4+2], ir=U[ge*4+3];
    float Y4=SQ3*ux*uy, Y5=SQ3*uy*uz, Y6=0.5f*(3.f*uz*uz-1.f);
    float Y7=SQ3*ux*uz, Y8=0.5f*SQ3*(ux*ux-uy*uy);
    float T = xs[0] + ux*xs[1]+uy*xs[2]+uz*xs[3]
            + Y4*xs[4]+Y5*xs[5]+Y6*xs[6]+Y7*xs[7]+Y8*xs[8];
    float X0 = xs[1] + SQ3*(uy*xs[4]+uz*xs[7]+ux*xs[8]);
    float X1 = xs[2] + SQ3*(ux*xs[4]+uz*xs[5]-uy*xs[8]);
    float X2 = xs[3] + SQ3*(uy*xs[5]+ux*xs[7]) + 3.f*uz*xs[6];
    acc[0] += gv*(RA+RB);
    acc[1] += gv*ux*RB; acc[2] += gv*uy*RB; acc[3] += gv*uz*RB;
    acc[4] += gv*Y4*RB; acc[5] += gv*Y5*RB; acc[6] += gv*Y6*RB;
    acc[7] += gv*Y7*RB; acc[8] += gv*Y8*RB;
    float gRB = gv*RB;
    float dotX = ux*X0 + uy*X1 + uz*X2;
    float v3 = gv*(xs[0]*PA + T*PB) - gRB*dotX*ir;
    float r4 = qreduce(gRB*X0, gRB*X1, gRB*X2, v3, f);
    float SR = __shfl(r4, f|3, 64);
    float um = (m==0)?ux : (m==1)?uy : (m==2)?uz : 0.f;
    float dd = r4*ir + SR*um;
    if (f<3) atomicAdd(&Fout[(size_t)(b*NA+i)*3+f], dd);
    sdd += dd;
  }
  float* ar = partP + (size_t)g*NNLF + xbase + f;
  #pragma unroll
  for (int l=0;l<L;l++) ar[l*F] = acc[l];
  if (f<3) atomicAdd(&Fout[(size_t)bn*3+f], -sdd);
}

// ---------------- layer node backward (4 waves, l-split, 4 slabs) -------------
template<bool WDX>
__global__ __launch_bounds__(256) void k_node_bwd(const float* __restrict__ dxIn,
    const float* __restrict__ partP, const float* __restrict__ y2W,
    const float* __restrict__ W1T, const float* __restrict__ W2T,
    float* __restrict__ dagg, float* __restrict__ dxOut){
  __shared__ float A[L*F];
  __shared__ float D3[L*F];
  __shared__ float Bb[L*F];
  __shared__ float prt[4][F];
  int t = threadIdx.x, g = t&63, w = t>>6;
  size_t base = ((size_t)blockIdx.x)*L*F;
  for (int idx=t; idx<L*F; idx+=256){
    float s = dxIn[base+idx];
    #pragma unroll
    for (int sl=0; sl<GSP; sl++) s += partP[(size_t)sl*NNLF + base + idx];
    A[idx]=s;
  }
  __syncthreads();
  float pc=0.f;
  for (int l=w; l<L; l+=4){
    const float* W = W2T + DEGC[l]*F*F + g;
    float s=0.f;
    for (int ff=0; ff<F; ff++) s += A[l*F+ff]*W[(size_t)ff*F];
    D3[l*F+g]=s;
    if (l>0) pc += s * y2W[base+l*F+g];
  }
  prt[w][g]=pc;
  __syncthreads();
  float sv = y2W[base+g];
  float sg = 1.f/(1.f+expf(-sv));
  for (int l=w; l<L; l+=4){
    float v;
    if (l==0){
      float sum = prt[0][g]+prt[1][g]+prt[2][g]+prt[3][g];
      v = D3[g]*sg*(1.f+sv*(1.f-sg)) + sum*sg*(1.f-sg);
    } else {
      v = D3[l*F+g]*sg;
    }
    Bb[l*F+g]=v;
  }
  __syncthreads();
  for (int l=w; l<L; l+=4){
    const float* W = W1T + DEGC[l]*F*F + g;
    float s=0.f;
    for (int ff=0; ff<F; ff++) s += Bb[l*F+ff]*W[(size_t)ff*F];
    dagg[base+l*F+g]=s;
    if (WDX) dxOut[base+l*F+g] = A[l*F+g] + s;
  }
}

// ---------------- layer edge backward (1-wave, split, force atomics) ----------
template<bool WDX, bool FIRST>
__global__ __launch_bounds__(64,4) void k_edge_bwd(const float* __restrict__ xI,
    const float* __restrict__ WA, const float* __restrict__ WB,
    const float* __restrict__ U, const float* __restrict__ Rr,
    const float* __restrict__ Rp, const float* __restrict__ dagg,
    float* __restrict__ partP, float* Fout){
  int bid = blockIdx.x;
  int g = bid & (GSP-1), bn = bid >> 2;
  int b = bn >> 7, j = bn & (NA-1);
  int f = threadIdx.x, m = f & 3;
  float wa[K], wb[K];
  #pragma unroll
  for (int k=0;k<K;k++){ wa[k]=WA[k*F+f]; wb[k]=WB[k*F+f]; }
  size_t xbase = ((size_t)bn)*L*F;
  float xs[L];
  xs[0] = xI[xbase+f];
  #pragma unroll
  for (int l=1;l<L;l++) xs[l] = FIRST ? 0.f : xI[xbase+l*F+f];
  float acc[L]; float acc0=0.f;
  #pragma unroll
  for (int l=0;l<L;l++) acc[l]=0.f;
  float sdd=0.f;
  int i0 = g*NSUB, i1 = min(i0+NSUB, NA-1);
  #pragma unroll 2
  for (int ii=i0; ii<i1; ++ii){
    int i = ii + (ii>=j);
    int c = (j<i)? j : j-1;
    size_t ge = (size_t)b*EPN + i*(NA-1)+c;
    const float* gr = dagg + ((size_t)(b*NA+i))*L*F + f;
    float gl[L];
    #pragma unroll
    for (int l=0;l<L;l++) gl[l]=gr[l*F];
    const float* Re = Rr + ge*K;
    const float* Pe = Rp + ge*K;
    float RA=0.f,RB=0.f,PA=0.f,PB=0.f;
    #pragma unroll
    for (int k=0;k<K;k++){ float rk=Re[k],pk=Pe[k];
      RA+=rk*wa[k]; RB+=rk*wb[k]; PA+=pk*wa[k]; PB+=pk*wb[k]; }
    float ux=U[ge*4+0], uy=U[ge*4+1], uz=U[ge*4+2], ir=U[ge*4+3];
    float Y4=SQ3*ux*uy, Y5=SQ3*uy*uz, Y6=0.5f*(3.f*uz*uz-1.f);
    float Y7=SQ3*ux*uz, Y8=0.5f*SQ3*(ux*ux-uy*uy);
    float gy = gl[0] + gl[1]*ux+gl[2]*uy+gl[3]*uz
             + gl[4]*Y4+gl[5]*Y5+gl[6]*Y6+gl[7]*Y7+gl[8]*Y8;
    float gx;
    if (FIRST){
      gx = gl[0]*xs[0];
    } else {
      gx = 0.f;
      #pragma unroll
      for (int l=0;l<L;l++) gx += gl[l]*xs[l];
    }
    float G0 = gl[1] + SQ3*(uy*gl[4]+uz*gl[7]+ux*gl[8]);
    float G1 = gl[2] + SQ3*(ux*gl[4]+uz*gl[5]-uy*gl[8]);
    float G2 = gl[3] + SQ3*(uy*gl[5]+ux*gl[7]) + 3.f*uz*gl[6];
    if (WDX){
      acc0 += gy*RA;
      #pragma unroll
      for (int l=0;l<L;l++) acc[l] += gl[l]*RB;
    }
    float cm = RA*xs[0];
    float dotG = ux*G0 + uy*G1 + uz*G2;
    float v3 = gy*xs[0]*PA + gx*PB - cm*dotG*ir;
    float r4 = qreduce(cm*G0, cm*G1, cm*G2, v3, f);
    float SR = __shfl(r4, f|3, 64);
    float um = (m==0)?ux : (m==1)?uy : (m==2)?uz : 0.f;
    float dd = r4*ir + SR*um;
    if (f<3) atomicAdd(&Fout[(size_t)(b*NA+i)*3+f], dd);
    sdd += dd;
  }
  if (WDX){
    float* ar = partP + (size_t)g*NNLF + xbase + f;
    ar[0] = acc0 + acc[0];
    #pragma unroll
    for (int l=1;l<L;l++) ar[l*F] = acc[l];
  }
  if (f<3) atomicAdd(&Fout[(size_t)bn*3+f], -sdd);
}

} // anonymous namespace

extern "C" void kernel_launch(void* const* d_in, const int* in_sizes, int n_in,
                              void* d_out, int out_size, void* d_ws, size_t ws_size,
                              hipStream_t stream){
  (void)in_sizes; (void)n_in; (void)out_size; (void)ws_size;
  const int*   z     = (const int*)  d_in[0];
  const float* pos   = (const float*)d_in[1];
  const float* emb   = (const float*)d_in[2];
  const float* WA    = (const float*)d_in[3];
  const float* WB    = (const float*)d_in[4];
  const float* W1    = (const float*)d_in[5];
  const float* b1    = (const float*)d_in[6];
  const float* W2    = (const float*)d_in[7];
  const float* W1s   = (const float*)d_in[8];
  const float* b1s   = (const float*)d_in[9];
  const float* W2s   = (const float*)d_in[10];
  const float* wout  = (const float*)d_in[11];
  const float* ebias = (const float*)d_in[12];
  const int*   dsti  = (const int*)  d_in[13];
  const int*   srci  = (const int*)  d_in[14];

  float* w    = (float*)d_ws;
  float* U    = w;                          // BE*4
  float* Rr   = U    + (size_t)BE*4;        // BE*16
  float* Rp   = Rr   + (size_t)BE*16;       // BE*16
  float* x0   = Rp   + (size_t)BE*16;       // NNLF
  float* x1   = x0   + NNLF;                // NNLF
  float* x2   = x1   + NNLF;                // NNLF
  float* y2b  = x2   + NNLF;                // 2*NNLF
  float* part = y2b  + 2*(size_t)NNLF;      // GSP*NNLF
  float* yRp  = part + (size_t)GSP*NNLF;    // GSP*BNF
  float* pW   = yRp  + (size_t)GSP*BNF;     // BNF
  float* dyR  = pW   + BNF;                 // BNF
  float* dxA  = dyR  + BNF;                 // NNLF
  float* dxO  = dxA  + NNLF;                // NNLF
  float* dagg = dxO  + NNLF;                // NNLF
  float* W1T  = dagg + NNLF;                // 6*F*F
  float* W2T  = W1T  + 6*F*F;               // 6*F*F
  float* W1sT = W2T  + 6*F*F;               // F*F
  float* dspv = W1sT + F*F;                 // F

  float* Eout = (float*)d_out;
  float* Fout = Eout + NB;

  dim3 bn(NB*NA);
  dim3 be(NB*NA*GSP);

  k_prep  <<<126, 256, 0, stream>>>(W1, W2, W1s, W2s, wout, W1T, W2T, W1sT, dspv, Eout);
  k_geom  <<<(BE+255)/256, 256, 0, stream>>>(pos, dsti, srci, U, Rr, Rp);
  k_init_x<<<bn, 64, 0, stream>>>(z, emb, x0);

  // layer 0
  k_edge_fwd<true ><<<be, 64, 0, stream>>>(x0, WA,     WB,     U, Rr, part);
  k_node_fwd<<<bn, 256, 0, stream>>>(x0, part, W1,       b1,   W2,       y2b,      x1);
  // layer 1
  k_edge_fwd<false><<<be, 64, 0, stream>>>(x1, WA+K*F, WB+K*F, U, Rr, part);
  k_node_fwd<<<bn, 256, 0, stream>>>(x1, part, W1+3*F*F, b1+F, W2+3*F*F, y2b+NNLF, x2);
  // readout
  k_redge_fwd<<<be, 64, 0, stream>>>(x2, WA+2*K*F, WB+2*K*F, U, Rr, yRp);
  k_rnode_fwd<<<bn, 256, 0, stream>>>(z, x2, yRp, W1s, b1s, W2s, wout, ebias, pW, Eout);

  // backward
  k_rnode_bwd<<<bn, 256, 0, stream>>>(pW, dspv, W1sT, wout, dyR, dxA);
  k_redge_bwd<<<be, 64, 0, stream>>>(x2, WA+2*K*F, WB+2*K*F, U, Rr, Rp, dyR, part, Fout);
  // layer 1 bwd
  k_node_bwd<true ><<<bn, 256, 0, stream>>>(dxA, part, y2b+NNLF, W1T+3*F*F, W2T+3*F*F, dagg, dxO);
  k_edge_bwd<true ,false><<<be, 64, 0, stream>>>(x1, WA+K*F, WB+K*F, U, Rr, Rp, dagg, part, Fout);
  // layer 0 bwd
  k_node_bwd<false><<<bn, 256, 0, stream>>>(dxO, part, y2b, W1T, W2T, dagg, nullptr);
  k_edge_bwd<false,true ><<<be, 64, 0, stream>>>(x0, WA, WB, U, Rr, Rp, dagg, nullptr, Fout);
}